// Round 11
// baseline (261.727 us; speedup 1.0000x reference)
//
#include <hip/hip_runtime.h>

typedef __attribute__((ext_vector_type(4))) float f32x4;
typedef __attribute__((ext_vector_type(16))) float f32x16;
typedef __attribute__((ext_vector_type(8))) short bf16x8;
typedef __attribute__((ext_vector_type(4))) unsigned u32x4;

#define DEV __device__ __forceinline__

DEV unsigned short f2bf(float f) {            // RTNE f32 -> bf16
  unsigned u = __float_as_uint(f);
  unsigned r = (u + 0x7FFFu + ((u >> 16) & 1u)) >> 16;
  return (unsigned short)r;
}
DEV float bf2f(unsigned short h) { return __uint_as_float(((unsigned)h) << 16); }

DEV unsigned cvtpk(float lo, float hi) {      // packed f32x2 -> bf16x2 (HW RTNE)
  unsigned r;
  asm("v_cvt_pk_bf16_f32 %0, %1, %2" : "=v"(r) : "v"(lo), "v"(hi));
  return r;
}
DEV bf16x8 frag4(unsigned a, unsigned b, unsigned c, unsigned d) {
  u32x4 u = {a, b, c, d};
  return __builtin_bit_cast(bf16x8, u);
}

typedef __attribute__((address_space(1))) void gas_t;
typedef __attribute__((address_space(3))) void las_t;
DEV void async16(void* lds, const void* g) {
  __builtin_amdgcn_global_load_lds((gas_t*)g, (las_t*)lds, 16, 0, 0);
}

// ---------------- elementwise cast: f32 -> bf16, 8 elems/thread ----------------
__global__ void cast_x(const float* __restrict__ x, unsigned short* __restrict__ y, int n8) {
  int idx = blockIdx.x * blockDim.x + threadIdx.x;
  int stride = gridDim.x * blockDim.x;
  for (; idx < n8; idx += stride) {
    const float4* p = (const float4*)(x + (size_t)idx * 8);
    float4 v0 = p[0], v1 = p[1];
    bf16x8 o;
    o[0] = (short)f2bf(v0.x); o[1] = (short)f2bf(v0.y);
    o[2] = (short)f2bf(v0.z); o[3] = (short)f2bf(v0.w);
    o[4] = (short)f2bf(v1.x); o[5] = (short)f2bf(v1.y);
    o[6] = (short)f2bf(v1.z); o[7] = (short)f2bf(v1.w);
    *(bf16x8*)(y + (size_t)idx * 8) = o;
  }
}

// ---------------- transpose + cast: W[K][N] f32 -> Wt[N][K] bf16 ----------------
__global__ void transpose_cast(const float* __restrict__ W, unsigned short* __restrict__ Wt,
                               int Kdim, int Nw) {
  __shared__ float tile[32][33];
  int n0 = blockIdx.x * 32, k0 = blockIdx.y * 32;
  int tx = threadIdx.x, ty = threadIdx.y;
#pragma unroll
  for (int r = ty; r < 32; r += 8)
    tile[r][tx] = W[(size_t)(k0 + r) * Nw + n0 + tx];
  __syncthreads();
#pragma unroll
  for (int r = ty; r < 32; r += 8)
    Wt[(size_t)(n0 + r) * Kdim + k0 + tx] = f2bf(tile[tx][r]);
}

// -------- GEMM, 8-phase-style deep pipeline: BM=256 BN=128 BK=64, 8 waves -----
// Triple-buffered LDS (lead = 2 K-tiles), 4 phases/K-tile, counted vmcnt(6),
// raw barriers + lgkmcnt(0)+sched_barrier (rule #18), granule^(row&7) swizzle
// staged via pre-swizzled global source (rule #21). T1 XCD swizzle (nwg%8==0).
template <int EPI>
__global__ __launch_bounds__(512, 1)
void gemm_bt(const unsigned short* __restrict__ A, const unsigned short* __restrict__ Bt,
             int Kr, float* __restrict__ Cf, int Nr,
             unsigned short* __restrict__ Qn, unsigned short* __restrict__ Kn,
             unsigned short* __restrict__ Vt) {
  __shared__ __align__(16) unsigned short Lds[3 * 24576];  // 144 KB: 3 x (A 32K + B 16K)
  const int t = threadIdx.x, lane = t & 63;
  const int w = t >> 6, wm = w >> 1, wn = w & 1;           // 4 M-waves x 2 N-waves
  const int lo = lane & 15, hi = lane >> 4;
  const int swz8 = lo & 7;
  const int nwg = gridDim.x;
  const int bid0 = blockIdx.x;
  const int sw = (bid0 & 7) * (nwg >> 3) + (bid0 >> 3);
  const int m0 = (sw & 15) * 256, n0 = (sw >> 4) * 128;

  unsigned short* b0 = Lds;            // tile j   (compute)
  unsigned short* b1 = Lds + 24576;    // tile j+1 (landed/landing)
  unsigned short* b2 = Lds + 49152;    // tile j+2 (staging target)

  // A-tile: 256 rows x 64 cols = 2048 granules (4 insts/thread); B: 128 rows = 2 insts.
#define SG_A(buf, kt_, u_) { int gi = (u_) * 512 + t; int rw = gi >> 3;              \
    int g = (gi & 7) ^ (rw & 7);                                                     \
    async16((buf) + gi * 8, A + (size_t)(m0 + rw) * Kr + (kt_) + g * 8); }
#define SG_B(buf, kt_, u_) { int gi = (u_) * 512 + t; int rw = gi >> 3;              \
    int g = (gi & 7) ^ (rw & 7);                                                     \
    async16((buf) + 16384 + gi * 8, Bt + (size_t)(n0 + rw) * Kr + (kt_) + g * 8); }

  f32x4 acc[4][4] = {};

  // prologue: tile0 -> b0, tile1 -> b1 (12 loads/thread); wait tile0 (vmcnt 6)
  SG_A(b0, 0, 0) SG_A(b0, 0, 1) SG_A(b0, 0, 2) SG_A(b0, 0, 3)
  SG_B(b0, 0, 0) SG_B(b0, 0, 1)
  SG_A(b1, 64, 0) SG_A(b1, 64, 1) SG_A(b1, 64, 2) SG_A(b1, 64, 3)
  SG_B(b1, 64, 0) SG_B(b1, 64, 1)
  asm volatile("s_waitcnt vmcnt(6)" ::: "memory");
  __builtin_amdgcn_s_barrier();

  const int nt = Kr >> 6;   // 32
  for (int j = 0; j < nt; ++j) {
    const bool pf = (j + 2 < nt);
    const int kt2 = (j + 2) << 6;
    bf16x8 bfr[4][2];
#pragma unroll
    for (int p = 0; p < 4; ++p) {
      // ---- ds_read this phase's fragments from b0 ----
      bf16x8 af[2];
      {
        const unsigned short* ab = b0 + (wm * 64 + p * 16 + lo) * 64;
        af[0] = *(const bf16x8*)(ab + (((0 + hi) ^ swz8) << 3));
        af[1] = *(const bf16x8*)(ab + (((4 + hi) ^ swz8) << 3));
      }
      if (p == 0) {
#pragma unroll
        for (int nn = 0; nn < 4; ++nn) {
          const unsigned short* bb = b0 + 16384 + (wn * 64 + nn * 16 + lo) * 64;
          bfr[nn][0] = *(const bf16x8*)(bb + (((0 + hi) ^ swz8) << 3));
          bfr[nn][1] = *(const bf16x8*)(bb + (((4 + hi) ^ swz8) << 3));
        }
      }
      // ---- stage this phase's share of tile j+2 into b2 ----
      if (pf) {
        if (p == 0)      { SG_A(b2, kt2, 0) SG_A(b2, kt2, 1) }
        else if (p == 1) { SG_A(b2, kt2, 2) SG_A(b2, kt2, 3) }
        else if (p == 2) { SG_B(b2, kt2, 0) }
        else             { SG_B(b2, kt2, 1) }
      }
      __builtin_amdgcn_s_barrier();
      asm volatile("s_waitcnt lgkmcnt(0)" ::: "memory");
      __builtin_amdgcn_sched_barrier(0);
      __builtin_amdgcn_s_setprio(1);
#pragma unroll
      for (int nn = 0; nn < 4; ++nn) {
        acc[p][nn] = __builtin_amdgcn_mfma_f32_16x16x32_bf16(af[0], bfr[nn][0], acc[p][nn], 0, 0, 0);
        acc[p][nn] = __builtin_amdgcn_mfma_f32_16x16x32_bf16(af[1], bfr[nn][1], acc[p][nn], 0, 0, 0);
      }
      __builtin_amdgcn_s_setprio(0);
      if (p == 3) {   // gate: tile j+1 landed; tile j+2's 6 loads stay in flight
        if (pf) asm volatile("s_waitcnt vmcnt(6)" ::: "memory");
        else    asm volatile("s_waitcnt vmcnt(0)" ::: "memory");
      }
      __builtin_amdgcn_s_barrier();
    }
    unsigned short* tb = b0; b0 = b1; b1 = b2; b2 = tb;
  }

  // ---- epilogue ----
#pragma unroll
  for (int mi = 0; mi < 4; ++mi)
#pragma unroll
    for (int ni = 0; ni < 4; ++ni)
#pragma unroll
      for (int i = 0; i < 4; ++i) {
        int gm = m0 + wm * 64 + mi * 16 + hi * 4 + i;
        int gn = n0 + wn * 64 + ni * 16 + lo;
        float v = acc[mi][ni][i];
        if (EPI == 0) {
          Cf[(size_t)gm * Nr + gn] = v;
        } else {
          unsigned short bv = f2bf(v);
          int bb = gm >> 11, tt = gm & 2047;
          if (gn < 2048) {                      // Q: [b][h][t][d]
            int hh = gn >> 7, dd = gn & 127;
            Qn[(((size_t)bb * 16 + hh) * 2048 + tt) * 128 + dd] = bv;
          } else if (gn < 2560) {               // K: [b][hkv][t][d]
            int g2 = gn - 2048, hh = g2 >> 7, dd = g2 & 127;
            Kn[(((size_t)bb * 4 + hh) * 2048 + tt) * 128 + dd] = bv;
          } else {                              // V^T: [b][hkv][d][t]
            int g2 = gn - 2560, hh = g2 >> 7, dd = g2 & 127;
            Vt[(((size_t)bb * 4 + hh) * 128 + dd) * 2048 + tt] = bv;
          }
        }
      }
}

// ---------------- QK RMS-norm (in place); Q also gets (1/sqrt(D))*log2(e) ------
__global__ __launch_bounds__(256)
void qk_norm(unsigned short* __restrict__ Qn, unsigned short* __restrict__ Kn, float qscale) {
  int row = blockIdx.x * 4 + (threadIdx.x >> 6);
  int lane = threadIdx.x & 63;
  unsigned short* base;
  float scl;
  if (row < 65536) { base = Qn + (size_t)row * 128; scl = qscale; }
  else             { base = Kn + (size_t)(row - 65536) * 128; scl = 1.0f; }
  unsigned v = *(const unsigned*)(base + lane * 2);
  float a = bf2f((unsigned short)(v & 0xffffu));
  float b = bf2f((unsigned short)(v >> 16));
  float ss = a * a + b * b;
#pragma unroll
  for (int m = 1; m < 64; m <<= 1) ss += __shfl_xor(ss, m, 64);
  float r = rsqrtf(ss * (1.0f / 128.0f) + 1e-6f) * scl;
  *(unsigned*)(base + lane * 2) = ((unsigned)f2bf(b * r) << 16) | (unsigned)f2bf(a * r);
}

// ---------------- fragmentize V into MFMA-consumption order (r8-verified) ------
__global__ __launch_bounds__(256)
void fragV(const unsigned short* __restrict__ Vt, unsigned short* __restrict__ Vf) {
  int tid = blockIdx.x * 256 + threadIdx.x;      // 262144 threads
  int bhkv = tid >> 15, c = tid & 32767;
  int lane = c & 63, tile = c >> 10, mid = (c >> 6) & 15;
  int dt = mid >> 2, g2 = mid & 3;
  int d = dt * 32 + (lane & 31);
  int g = g2 * 2 + (lane >> 5);
  int k0 = tile * 64 + g * 8;
  const uint4* src = (const uint4*)(Vt + ((size_t)bhkv * 128 + d) * 2048 + k0);
  uint4* dst = (uint4*)(Vf + (size_t)bhkv * 262144 + (size_t)c * 8);
  *dst = *src;
}

// ---------------- flash attention: K in LDS dbuf, V from global (frag order) --
__global__ __launch_bounds__(256, 2)
void attn(const unsigned short* __restrict__ Q, const unsigned short* __restrict__ Kk,
          const unsigned short* __restrict__ Vf, unsigned short* __restrict__ AO) {
  const int bid = blockIdx.x;                 // 512 = 8(xcd) x 4(h2) x 16(qx)
  const int x = bid & 7, r2 = bid >> 3;
  const int h2 = r2 & 3, qx = r2 >> 2;
  const int b = x >> 2, hkv = x & 3;
  const int h = hkv * 4 + h2, bh = b * 16 + h, bhkv = b * 4 + hkv;
  const int t = threadIdx.x;
  const int w = t >> 6, lane = t & 63;
  const int qi = lane & 31, h1 = lane >> 5;
  const unsigned short* Qb = Q  + (size_t)bh * 2048 * 128;
  const unsigned short* Kb = Kk + (size_t)bhkv * 2048 * 128;
  const unsigned short* Vfb = Vf + (size_t)bhkv * 262144;
  const int q0 = qx * 128 + w * 32;

  __shared__ __align__(16) unsigned short Klds[2][64 * 128];  // 32 KB, granule^(row&15)

  bf16x8 qf[8];
#pragma unroll
  for (int s = 0; s < 8; ++s)
    qf[s] = *(const bf16x8*)&Qb[(size_t)(q0 + qi) * 128 + s * 16 + h1 * 8];

  f32x16 Oc[4] = {};            // O^T acc: col=q (lane), row=d-offset
  float mrow = -1e30f, srow = 0.f;

#define STAGE_K(bufi, kt_)                                                       \
  {                                                                              \
    const unsigned short* gK = Kb + (size_t)(kt_) * 128;                         \
    _Pragma("unroll")                                                            \
    for (int j = 0; j < 4; ++j) {                                                \
      int gi = j * 256 + t;                                                      \
      int kr = gi >> 4, kg = (gi & 15) ^ (kr & 15);                              \
      async16(&Klds[bufi][gi * 8], gK + (size_t)kr * 128 + kg * 8);              \
    }                                                                            \
  }

  STAGE_K(0, 0);
  __syncthreads();

  int cur = 0;
  for (int ti = 0; ti < 32; ++ti) {
    if (ti + 1 < 32) STAGE_K(cur ^ 1, (ti + 1) * 64);

    // ---- V prefetch for this tile (global, fragment-ordered, coalesced) ----
    bf16x8 vf0[2][4], vf1[2][4];   // [mt][dt]
#pragma unroll
    for (int mt = 0; mt < 2; ++mt)
#pragma unroll
      for (int dt = 0; dt < 4; ++dt) {
        const unsigned short* vp = Vfb + ((size_t)((ti * 4 + dt) * 4 + mt * 2)) * 512 + lane * 8;
        vf0[mt][dt] = *(const bf16x8*)(vp);
        vf1[mt][dt] = *(const bf16x8*)(vp + 512);
      }

    const unsigned short* KL = Klds[cur];

    // ---- QK^T (swapped): S[mt] = K_tile^T-frag x Q-frag; lane q = qi ----
    f32x16 S[2] = {};
    __builtin_amdgcn_s_setprio(1);
#pragma unroll
    for (int mt = 0; mt < 2; ++mt) {
      const int krow = mt * 32 + qi;
      const unsigned short* krp = KL + krow * 128;
      const int rswz = krow & 15;
#pragma unroll
      for (int s = 0; s < 8; ++s) {
        bf16x8 kf = *(const bf16x8*)(krp + (((2 * s + h1) ^ rswz) << 3));
        S[mt] = __builtin_amdgcn_mfma_f32_32x32x16_bf16(kf, qf[s], S[mt], 0, 0, 0);
      }
    }
    __builtin_amdgcn_s_setprio(0);
    // lane holds P[q=qi][key = mt*32 + (r&3) + 8*(r>>2) + 4*h1], r=0..15

    // ---- in-register online softmax (base-2), tree reductions ----
    float t8[8];
#pragma unroll
    for (int r = 0; r < 8; ++r)
      t8[r] = fmaxf(fmaxf(S[0][r], S[0][r + 8]), fmaxf(S[1][r], S[1][r + 8]));
#pragma unroll
    for (int r = 0; r < 4; ++r) t8[r] = fmaxf(t8[r], t8[r + 4]);
    float mx = fmaxf(fmaxf(t8[0], t8[1]), fmaxf(t8[2], t8[3]));
    mx = fmaxf(mx, __shfl_xor(mx, 32, 64));
    if (__any(mx > mrow + 8.0f)) {             // defer-max THR=8 (base-2)
      float mnew = fmaxf(mrow, mx);
      float al = __builtin_amdgcn_exp2f(mrow - mnew);
      mrow = mnew;
      srow *= al;
#pragma unroll
      for (int dt = 0; dt < 4; ++dt)
#pragma unroll
        for (int r = 0; r < 16; ++r) Oc[dt][r] *= al;
    }
#pragma unroll
    for (int mt = 0; mt < 2; ++mt)
#pragma unroll
      for (int r = 0; r < 16; ++r)
        S[mt][r] = __builtin_amdgcn_exp2f(S[mt][r] - mrow);
    float s8[8];
#pragma unroll
    for (int r = 0; r < 8; ++r)
      s8[r] = (S[0][r] + S[0][r + 8]) + (S[1][r] + S[1][r + 8]);
#pragma unroll
    for (int r = 0; r < 4; ++r) s8[r] += s8[r + 4];
    float rs = (s8[0] + s8[1]) + (s8[2] + s8[3]);
    rs += __shfl_xor(rs, 32, 64);
    srow += rs;

    // ---- P -> bf16 (HW cvt_pk), cross-half exchange, PV (V regs) ----
    __builtin_amdgcn_s_setprio(1);
#pragma unroll
    for (int mt = 0; mt < 2; ++mt) {
      unsigned wd[8];
#pragma unroll
      for (int i2 = 0; i2 < 8; ++i2) wd[i2] = cvtpk(S[mt][2 * i2], S[mt][2 * i2 + 1]);
      unsigned r0 = __shfl_xor(h1 ? wd[0] : wd[2], 32, 64);
      unsigned r1 = __shfl_xor(h1 ? wd[1] : wd[3], 32, 64);
      unsigned r2_ = __shfl_xor(h1 ? wd[4] : wd[6], 32, 64);
      unsigned r3 = __shfl_xor(h1 ? wd[5] : wd[7], 32, 64);
      bf16x8 pf0 = frag4(h1 ? r0 : wd[0], h1 ? r1 : wd[1], h1 ? wd[2] : r0, h1 ? wd[3] : r1);
      bf16x8 pf1 = frag4(h1 ? r2_ : wd[4], h1 ? r3 : wd[5], h1 ? wd[6] : r2_, h1 ? wd[7] : r3);
#pragma unroll
      for (int dt = 0; dt < 4; ++dt) {
        Oc[dt] = __builtin_amdgcn_mfma_f32_32x32x16_bf16(vf0[mt][dt], pf0, Oc[dt], 0, 0, 0);
        Oc[dt] = __builtin_amdgcn_mfma_f32_32x32x16_bf16(vf1[mt][dt], pf1, Oc[dt], 0, 0, 0);
      }
    }
    __builtin_amdgcn_s_setprio(0);

    __syncthreads();  // K prefetch landed + all LDS reads done before overwrite
    cur ^= 1;
  }

  // ---- epilogue: O = Oc / srow; lane writes 32 d-values for its q row ----
  const float inv = 1.0f / srow;
  const size_t orow = ((size_t)(b * 2048 + q0 + qi)) * 2048 + h * 128;
#pragma unroll
  for (int dt = 0; dt < 4; ++dt)
#pragma unroll
    for (int rq = 0; rq < 4; ++rq) {
      int d0 = dt * 32 + 8 * rq + 4 * h1;
      unsigned u0 = cvtpk(Oc[dt][4 * rq + 0] * inv, Oc[dt][4 * rq + 1] * inv);
      unsigned u1 = cvtpk(Oc[dt][4 * rq + 2] * inv, Oc[dt][4 * rq + 3] * inv);
      uint2 st = {u0, u1};
      *(uint2*)((unsigned short*)AO + orow + d0) = st;
    }
}

// ------------------------------- launcher -------------------------------------
extern "C" void kernel_launch(void* const* d_in, const int* in_sizes, int n_in,
                              void* d_out, int out_size, void* d_ws, size_t ws_size,
                              hipStream_t stream) {
  const float* x_q = (const float*)d_in[0];
  const float* Wq  = (const float*)d_in[1];
  const float* Wk  = (const float*)d_in[2];
  const float* Wv  = (const float*)d_in[3];
  const float* Wo  = (const float*)d_in[4];
  float* out = (float*)d_out;

  char* ws = (char*)d_ws;
  unsigned short* Xb    = (unsigned short*)(ws);             // 16.8 MB (reused as AO)
  unsigned short* WqkvT = (unsigned short*)(ws + 16777216);  // 12.6 MB (reused as Vf)
  unsigned short* WoT   = (unsigned short*)(ws + 29360128);  //  8.4 MB
  unsigned short* Qn    = (unsigned short*)(ws + 37748736);  // 16.8 MB
  unsigned short* Kn    = (unsigned short*)(ws + 54525952);  //  4.2 MB
  unsigned short* Vt    = (unsigned short*)(ws + 58720256);  //  4.2 MB
  unsigned short* AO    = Xb;
  unsigned short* Vf    = WqkvT;                             // 4.2 MB (after gemm1)

  cast_x<<<2048, 256, 0, stream>>>(x_q, Xb, (4096 * 2048) / 8);
  transpose_cast<<<dim3(2048 / 32, 2048 / 32), dim3(32, 8), 0, stream>>>(Wq, WqkvT, 2048, 2048);
  transpose_cast<<<dim3(512 / 32, 2048 / 32), dim3(32, 8), 0, stream>>>(Wk, WqkvT + 2048 * 2048, 2048, 512);
  transpose_cast<<<dim3(512 / 32, 2048 / 32), dim3(32, 8), 0, stream>>>(Wv, WqkvT + 2560 * 2048, 2048, 512);
  transpose_cast<<<dim3(2048 / 32, 2048 / 32), dim3(32, 8), 0, stream>>>(Wo, WoT, 2048, 2048);

  gemm_bt<1><<<384, 512, 0, stream>>>(Xb, WqkvT, 2048, nullptr, 0, Qn, Kn, Vt);
  // Q scale = (1/sqrt(128)) * log2(e)  -> softmax runs in base-2
  qk_norm<<<(65536 + 16384) / 4, 256, 0, stream>>>(Qn, Kn, 0.12751742f);
  fragV<<<1024, 256, 0, stream>>>(Vt, Vf);
  attn<<<512, 256, 0, stream>>>(Qn, Kn, Vf, AO);
  gemm_bt<0><<<256, 512, 0, stream>>>(AO, WoT, 2048, out, 2048,
                                      nullptr, nullptr, nullptr);
}

// Round 12
// 239.114 us; speedup vs baseline: 1.0946x; 1.0946x over previous
//
#include <hip/hip_runtime.h>

typedef __attribute__((ext_vector_type(4))) float f32x4;
typedef __attribute__((ext_vector_type(16))) float f32x16;
typedef __attribute__((ext_vector_type(8))) short bf16x8;
typedef __attribute__((ext_vector_type(4))) unsigned u32x4;

#define DEV __device__ __forceinline__

DEV unsigned short f2bf(float f) {            // RTNE f32 -> bf16
  unsigned u = __float_as_uint(f);
  unsigned r = (u + 0x7FFFu + ((u >> 16) & 1u)) >> 16;
  return (unsigned short)r;
}
DEV float bf2f(unsigned short h) { return __uint_as_float(((unsigned)h) << 16); }

DEV unsigned cvtpk(float lo, float hi) {      // packed f32x2 -> bf16x2 (HW RTNE)
  unsigned r;
  asm("v_cvt_pk_bf16_f32 %0, %1, %2" : "=v"(r) : "v"(lo), "v"(hi));
  return r;
}
DEV bf16x8 frag4(unsigned a, unsigned b, unsigned c, unsigned d) {
  u32x4 u = {a, b, c, d};
  return __builtin_bit_cast(bf16x8, u);
}

typedef __attribute__((address_space(1))) void gas_t;
typedef __attribute__((address_space(3))) void las_t;
DEV void async16(void* lds, const void* g) {
  __builtin_amdgcn_global_load_lds((gas_t*)g, (las_t*)lds, 16, 0, 0);
}

// ---------------- elementwise cast: f32 -> bf16, 8 elems/thread ----------------
__global__ void cast_x(const float* __restrict__ x, unsigned short* __restrict__ y, int n8) {
  int idx = blockIdx.x * blockDim.x + threadIdx.x;
  int stride = gridDim.x * blockDim.x;
  for (; idx < n8; idx += stride) {
    const float4* p = (const float4*)(x + (size_t)idx * 8);
    float4 v0 = p[0], v1 = p[1];
    bf16x8 o;
    o[0] = (short)f2bf(v0.x); o[1] = (short)f2bf(v0.y);
    o[2] = (short)f2bf(v0.z); o[3] = (short)f2bf(v0.w);
    o[4] = (short)f2bf(v1.x); o[5] = (short)f2bf(v1.y);
    o[6] = (short)f2bf(v1.z); o[7] = (short)f2bf(v1.w);
    *(bf16x8*)(y + (size_t)idx * 8) = o;
  }
}

// ---------------- transpose + cast: W[K][N] f32 -> Wt[N][K] bf16 ----------------
__global__ void transpose_cast(const float* __restrict__ W, unsigned short* __restrict__ Wt,
                               int Kdim, int Nw) {
  __shared__ float tile[32][33];
  int n0 = blockIdx.x * 32, k0 = blockIdx.y * 32;
  int tx = threadIdx.x, ty = threadIdx.y;
#pragma unroll
  for (int r = ty; r < 32; r += 8)
    tile[r][tx] = W[(size_t)(k0 + r) * Nw + n0 + tx];
  __syncthreads();
#pragma unroll
  for (int r = ty; r < 32; r += 8)
    Wt[(size_t)(n0 + r) * Kdim + k0 + tx] = f2bf(tile[tx][r]);
}

// ---------------- GEMM (m97 structure): A[M][K] x Bt[N][K] -------------------
// T1 XCD swizzle: column-chunked, bijective (nwg % 8 == 0, gridDim.y == 32).
// EPI==1 fuses QK RMS-norm into the epilogue (a Q/K row's 128 d-values lie
// entirely inside one 128-wide n-block; V region skips norm).
template <int EPI>
__global__ __launch_bounds__(256, 2)
void gemm_bt(const unsigned short* __restrict__ A, const unsigned short* __restrict__ Bt,
             int Kr, float* __restrict__ Cf, int Nr,
             unsigned short* __restrict__ Qn, unsigned short* __restrict__ Kn,
             unsigned short* __restrict__ Vt, float qscale) {
  __shared__ __align__(16) unsigned short lsA[128 * 32];
  __shared__ __align__(16) unsigned short lsB[128 * 32];
  const int t = threadIdx.x;
  const int lane = t & 63;
  const int w = t >> 6, wr = w >> 1, wc = w & 1;
  const int lo = lane & 15, hi = lane >> 4;
  const int nwg = gridDim.x * 32;
  const int bid0 = blockIdx.y * gridDim.x + blockIdx.x;
  const int sw = (bid0 & 7) * (nwg >> 3) + (bid0 >> 3);
  const int m0 = (sw & 31) * 128, n0 = (sw >> 5) * 128;

  const int c0 = t, c1 = t + 256;
  const unsigned short* gA0 = A + (size_t)(m0 + (c0 >> 2)) * Kr + (c0 & 3) * 8;
  const unsigned short* gA1 = A + (size_t)(m0 + (c1 >> 2)) * Kr + (c1 & 3) * 8;
  const unsigned short* gB0 = Bt + (size_t)(n0 + (c0 >> 2)) * Kr + (c0 & 3) * 8;
  const unsigned short* gB1 = Bt + (size_t)(n0 + (c1 >> 2)) * Kr + (c1 & 3) * 8;
  unsigned short* lA0 = lsA + c0 * 8;
  unsigned short* lA1 = lsA + c1 * 8;
  unsigned short* lB0 = lsB + c0 * 8;
  unsigned short* lB1 = lsB + c1 * 8;

  f32x4 acc[4][4] = {};

  for (int kt = 0; kt < Kr; kt += 32) {
    async16(lA0, gA0 + kt);
    async16(lA1, gA1 + kt);
    async16(lB0, gB0 + kt);
    async16(lB1, gB1 + kt);
    __syncthreads();
    bf16x8 af[4], bfr[4];
#pragma unroll
    for (int i = 0; i < 4; ++i) {
      af[i]  = *(const bf16x8*)&lsA[(wr * 64 + i * 16 + lo) * 32 + hi * 8];
      bfr[i] = *(const bf16x8*)&lsB[(wc * 64 + i * 16 + lo) * 32 + hi * 8];
    }
#pragma unroll
    for (int mi = 0; mi < 4; ++mi)
#pragma unroll
      for (int ni = 0; ni < 4; ++ni)
        acc[mi][ni] = __builtin_amdgcn_mfma_f32_16x16x32_bf16(af[mi], bfr[ni], acc[mi][ni], 0, 0, 0);
    __syncthreads();
  }

  // ---- fused QK RMS-norm factors (EPI==1, Q/K blocks only) ----
  float rr[4][4];
  if (EPI == 1 && n0 < 2560) {
    const float scl = (n0 < 2048) ? qscale : 1.0f;
    float p[4][4];
#pragma unroll
    for (int mi = 0; mi < 4; ++mi)
#pragma unroll
      for (int i = 0; i < 4; ++i) {
        float s = 0.f;
#pragma unroll
        for (int ni = 0; ni < 4; ++ni) s += acc[mi][ni][i] * acc[mi][ni][i];
        p[mi][i] = s;
      }
#pragma unroll
    for (int off = 1; off < 16; off <<= 1)
#pragma unroll
      for (int mi = 0; mi < 4; ++mi)
#pragma unroll
        for (int i = 0; i < 4; ++i) p[mi][i] += __shfl_xor(p[mi][i], off, 64);
    float* red = (float*)lsA;   // [4 wr][2 wc][64 rows] floats = 2 KB (lsA dead)
    if (lo == 0)
#pragma unroll
      for (int mi = 0; mi < 4; ++mi)
#pragma unroll
        for (int i = 0; i < 4; ++i)
          red[(wr * 2 + wc) * 64 + mi * 16 + hi * 4 + i] = p[mi][i];
    __syncthreads();
#pragma unroll
    for (int mi = 0; mi < 4; ++mi)
#pragma unroll
      for (int i = 0; i < 4; ++i) {
        float tot = p[mi][i] + red[(wr * 2 + (wc ^ 1)) * 64 + mi * 16 + hi * 4 + i];
        rr[mi][i] = rsqrtf(tot * (1.0f / 128.0f) + 1e-6f) * scl;
      }
  }

#pragma unroll
  for (int mi = 0; mi < 4; ++mi)
#pragma unroll
    for (int ni = 0; ni < 4; ++ni)
#pragma unroll
      for (int i = 0; i < 4; ++i) {
        int gm = m0 + wr * 64 + mi * 16 + hi * 4 + i;
        int gn = n0 + wc * 64 + ni * 16 + lo;
        float v = acc[mi][ni][i];
        if (EPI == 0) {
          Cf[(size_t)gm * Nr + gn] = v;
        } else {
          if (n0 < 2560) v *= rr[mi][i];        // fused RMS-norm (Q: +qscale)
          unsigned short bv = f2bf(v);
          int bb = gm >> 11, tt = gm & 2047;
          if (gn < 2048) {                      // Q: [b][h][t][d]
            int hh = gn >> 7, dd = gn & 127;
            Qn[(((size_t)bb * 16 + hh) * 2048 + tt) * 128 + dd] = bv;
          } else if (gn < 2560) {               // K: [b][hkv][t][d]
            int g2 = gn - 2048, hh = g2 >> 7, dd = g2 & 127;
            Kn[(((size_t)bb * 4 + hh) * 2048 + tt) * 128 + dd] = bv;
          } else {                              // V^T: [b][hkv][d][t]
            int g2 = gn - 2560, hh = g2 >> 7, dd = g2 & 127;
            Vt[(((size_t)bb * 4 + hh) * 128 + dd) * 2048 + tt] = bv;
          }
        }
      }
}

// ---------------- flash attention: swapped-QK^T 32x32 MFMA, in-register softmax
__global__ __launch_bounds__(256, 2)
void attn(const unsigned short* __restrict__ Q, const unsigned short* __restrict__ Kk,
          const unsigned short* __restrict__ Vt, unsigned short* __restrict__ AO) {
  const int bid = blockIdx.x;
  const int bh = (bid & 7) + 8 * (bid >> 7);   // XCD swizzle (512 % 8 == 0, bijective)
  const int qx = (bid >> 3) & 15;
  const int b = bh >> 4, h = bh & 15;
  const int hkv = h >> 2;
  const int t = threadIdx.x;
  const int w = t >> 6, lane = t & 63;
  const int qi = lane & 31, h1 = lane >> 5;
  const unsigned short* Qb = Q  + (size_t)bh * 2048 * 128;
  const unsigned short* Kb = Kk + (size_t)(b * 4 + hkv) * 2048 * 128;
  const unsigned short* Vb = Vt + (size_t)(b * 4 + hkv) * 128 * 2048;
  const int q0 = qx * 128 + w * 32;

  __shared__ __align__(16) unsigned short Klds[2][64 * 128];  // 32 KB, granule^(row&15)
  __shared__ __align__(16) unsigned short Vlds[2][128 * 64];  // 32 KB, granule^(row&7)

  bf16x8 qf[8];
#pragma unroll
  for (int s = 0; s < 8; ++s)
    qf[s] = *(const bf16x8*)&Qb[(size_t)(q0 + qi) * 128 + s * 16 + h1 * 8];

  f32x16 Oc[4] = {};            // O^T acc: col=q (lane), row=d-offset
  float mrow = -1e30f, srow = 0.f;

#define STAGE_KV(bufi, kt_)                                                      \
  {                                                                              \
    const unsigned short* gK = Kb + (size_t)(kt_) * 128;                         \
    const unsigned short* gV = Vb + (kt_);                                       \
    _Pragma("unroll")                                                            \
    for (int j = 0; j < 4; ++j) {                                                \
      int gi = j * 256 + t;                                                      \
      int kr = gi >> 4, kg = (gi & 15) ^ (kr & 15);                              \
      async16(&Klds[bufi][gi * 8], gK + (size_t)kr * 128 + kg * 8);              \
      int vr = gi >> 3, vg = (gi & 7) ^ (vr & 7);                                \
      async16(&Vlds[bufi][gi * 8], gV + (size_t)vr * 2048 + vg * 8);             \
    }                                                                            \
  }

  STAGE_KV(0, 0);
  __syncthreads();

  int cur = 0;
  for (int kt = 0; kt < 2048; kt += 64) {
    if (kt + 64 < 2048) STAGE_KV(cur ^ 1, kt + 64);

    const unsigned short* KL = Klds[cur];
    const unsigned short* VL = Vlds[cur];

    // ---- QK^T (swapped): S[mt] = K_tile^T-frag x Q-frag; lane q = qi ----
    f32x16 S[2] = {};
    __builtin_amdgcn_s_setprio(1);
#pragma unroll
    for (int mt = 0; mt < 2; ++mt) {
      const int krow = mt * 32 + qi;
      const unsigned short* krp = KL + krow * 128;
      const int rswz = krow & 15;
#pragma unroll
      for (int s = 0; s < 8; ++s) {
        bf16x8 kf = *(const bf16x8*)(krp + (((2 * s + h1) ^ rswz) << 3));
        S[mt] = __builtin_amdgcn_mfma_f32_32x32x16_bf16(kf, qf[s], S[mt], 0, 0, 0);
      }
    }
    __builtin_amdgcn_s_setprio(0);
    // lane holds P[q=qi][key = mt*32 + (r&3) + 8*(r>>2) + 4*h1], r=0..15

    // ---- in-register online softmax (base-2), tree reductions ----
    float t8[8];
#pragma unroll
    for (int r = 0; r < 8; ++r)
      t8[r] = fmaxf(fmaxf(S[0][r], S[0][r + 8]), fmaxf(S[1][r], S[1][r + 8]));
#pragma unroll
    for (int r = 0; r < 4; ++r) t8[r] = fmaxf(t8[r], t8[r + 4]);
    float mx = fmaxf(fmaxf(t8[0], t8[1]), fmaxf(t8[2], t8[3]));
    mx = fmaxf(mx, __shfl_xor(mx, 32, 64));
    if (__any(mx > mrow + 8.0f)) {             // defer-max THR=8 (base-2)
      float mnew = fmaxf(mrow, mx);
      float al = __builtin_amdgcn_exp2f(mrow - mnew);
      mrow = mnew;
      srow *= al;
#pragma unroll
      for (int dt = 0; dt < 4; ++dt)
#pragma unroll
        for (int r = 0; r < 16; ++r) Oc[dt][r] *= al;
    }
#pragma unroll
    for (int mt = 0; mt < 2; ++mt)
#pragma unroll
      for (int r = 0; r < 16; ++r)
        S[mt][r] = __builtin_amdgcn_exp2f(S[mt][r] - mrow);
    float s8[8];
#pragma unroll
    for (int r = 0; r < 8; ++r)
      s8[r] = (S[0][r] + S[0][r + 8]) + (S[1][r] + S[1][r + 8]);
#pragma unroll
    for (int r = 0; r < 4; ++r) s8[r] += s8[r + 4];
    float rs = (s8[0] + s8[1]) + (s8[2] + s8[3]);
    rs += __shfl_xor(rs, 32, 64);
    srow += rs;

    // ---- P -> bf16 (HW cvt_pk), cross-half exchange, PV ----
    __builtin_amdgcn_s_setprio(1);
#pragma unroll
    for (int mt = 0; mt < 2; ++mt) {
      unsigned wd[8];
#pragma unroll
      for (int i2 = 0; i2 < 8; ++i2) wd[i2] = cvtpk(S[mt][2 * i2], S[mt][2 * i2 + 1]);
      unsigned r0 = __shfl_xor(h1 ? wd[0] : wd[2], 32, 64);
      unsigned r1 = __shfl_xor(h1 ? wd[1] : wd[3], 32, 64);
      unsigned r2 = __shfl_xor(h1 ? wd[4] : wd[6], 32, 64);
      unsigned r3 = __shfl_xor(h1 ? wd[5] : wd[7], 32, 64);
      bf16x8 pf0 = frag4(h1 ? r0 : wd[0], h1 ? r1 : wd[1], h1 ? wd[2] : r0, h1 ? wd[3] : r1);
      bf16x8 pf1 = frag4(h1 ? r2 : wd[4], h1 ? r3 : wd[5], h1 ? wd[6] : r2, h1 ? wd[7] : r3);
#pragma unroll
      for (int dt = 0; dt < 4; ++dt) {
        const int vrow = dt * 32 + qi;
        const unsigned short* vrp = VL + vrow * 64;
        const int vswz = vrow & 7;
        bf16x8 v0 = *(const bf16x8*)(vrp + (((mt * 4 + 0 + h1) ^ vswz) << 3));
        bf16x8 v1 = *(const bf16x8*)(vrp + (((mt * 4 + 2 + h1) ^ vswz) << 3));
        Oc[dt] = __builtin_amdgcn_mfma_f32_32x32x16_bf16(v0, pf0, Oc[dt], 0, 0, 0);
        Oc[dt] = __builtin_amdgcn_mfma_f32_32x32x16_bf16(v1, pf1, Oc[dt], 0, 0, 0);
      }
    }
    __builtin_amdgcn_s_setprio(0);

    __syncthreads();  // prefetch landed + all LDS reads done before overwrite
    cur ^= 1;
  }

  // ---- epilogue: O = Oc / srow; lane writes 32 d-values for its q row ----
  const float inv = 1.0f / srow;
  const size_t orow = ((size_t)(b * 2048 + q0 + qi)) * 2048 + h * 128;
#pragma unroll
  for (int dt = 0; dt < 4; ++dt)
#pragma unroll
    for (int rq = 0; rq < 4; ++rq) {
      int d0 = dt * 32 + 8 * rq + 4 * h1;
      unsigned u0 = cvtpk(Oc[dt][4 * rq + 0] * inv, Oc[dt][4 * rq + 1] * inv);
      unsigned u1 = cvtpk(Oc[dt][4 * rq + 2] * inv, Oc[dt][4 * rq + 3] * inv);
      uint2 st = {u0, u1};
      *(uint2*)((unsigned short*)AO + orow + d0) = st;
    }
}

// ------------------------------- launcher -------------------------------------
extern "C" void kernel_launch(void* const* d_in, const int* in_sizes, int n_in,
                              void* d_out, int out_size, void* d_ws, size_t ws_size,
                              hipStream_t stream) {
  const float* x_q = (const float*)d_in[0];
  const float* Wq  = (const float*)d_in[1];
  const float* Wk  = (const float*)d_in[2];
  const float* Wv  = (const float*)d_in[3];
  const float* Wo  = (const float*)d_in[4];
  float* out = (float*)d_out;

  char* ws = (char*)d_ws;
  unsigned short* Xb    = (unsigned short*)(ws);             // 16.8 MB (reused as AO)
  unsigned short* WqkvT = (unsigned short*)(ws + 16777216);  // 12.6 MB
  unsigned short* WoT   = (unsigned short*)(ws + 29360128);  //  8.4 MB
  unsigned short* Qn    = (unsigned short*)(ws + 37748736);  // 16.8 MB
  unsigned short* Kn    = (unsigned short*)(ws + 54525952);  //  4.2 MB
  unsigned short* Vt    = (unsigned short*)(ws + 58720256);  //  4.2 MB
  unsigned short* AO    = Xb;

  cast_x<<<2048, 256, 0, stream>>>(x_q, Xb, (4096 * 2048) / 8);
  transpose_cast<<<dim3(2048 / 32, 2048 / 32), dim3(32, 8), 0, stream>>>(Wq, WqkvT, 2048, 2048);
  transpose_cast<<<dim3(512 / 32, 2048 / 32), dim3(32, 8), 0, stream>>>(Wk, WqkvT + 2048 * 2048, 2048, 512);
  transpose_cast<<<dim3(512 / 32, 2048 / 32), dim3(32, 8), 0, stream>>>(Wv, WqkvT + 2560 * 2048, 2048, 512);
  transpose_cast<<<dim3(2048 / 32, 2048 / 32), dim3(32, 8), 0, stream>>>(Wo, WoT, 2048, 2048);

  // Q scale = (1/sqrt(128)) * log2(e) -> softmax runs in base-2 (norm fused in epilogue)
  gemm_bt<1><<<dim3(3072 / 128, 4096 / 128), 256, 0, stream>>>(Xb, WqkvT, 2048, nullptr, 0,
                                                               Qn, Kn, Vt, 0.12751742f);
  attn<<<512, 256, 0, stream>>>(Qn, Kn, Vt, AO);
  gemm_bt<0><<<dim3(2048 / 128, 4096 / 128), 256, 0, stream>>>(AO, WoT, 2048, out, 2048,
                                                               nullptr, nullptr, nullptr, 0.f);
}

// Round 13
// 238.778 us; speedup vs baseline: 1.0961x; 1.0014x over previous
//
#include <hip/hip_runtime.h>

typedef __attribute__((ext_vector_type(4))) float f32x4;
typedef __attribute__((ext_vector_type(16))) float f32x16;
typedef __attribute__((ext_vector_type(8))) short bf16x8;
typedef __attribute__((ext_vector_type(4))) unsigned u32x4;

#define DEV __device__ __forceinline__

DEV unsigned short f2bf(float f) {            // RTNE f32 -> bf16
  unsigned u = __float_as_uint(f);
  unsigned r = (u + 0x7FFFu + ((u >> 16) & 1u)) >> 16;
  return (unsigned short)r;
}
DEV float bf2f(unsigned short h) { return __uint_as_float(((unsigned)h) << 16); }

DEV unsigned cvtpk(float lo, float hi) {      // packed f32x2 -> bf16x2 (HW RTNE)
  unsigned r;
  asm("v_cvt_pk_bf16_f32 %0, %1, %2" : "=v"(r) : "v"(lo), "v"(hi));
  return r;
}
DEV bf16x8 frag4(unsigned a, unsigned b, unsigned c, unsigned d) {
  u32x4 u = {a, b, c, d};
  return __builtin_bit_cast(bf16x8, u);
}

typedef __attribute__((address_space(1))) void gas_t;
typedef __attribute__((address_space(3))) void las_t;
DEV void async16(void* lds, const void* g) {
  __builtin_amdgcn_global_load_lds((gas_t*)g, (las_t*)lds, 16, 0, 0);
}

// ---------------- elementwise cast: f32 -> bf16, 8 elems/thread ----------------
__global__ void cast_x(const float* __restrict__ x, unsigned short* __restrict__ y, int n8) {
  int idx = blockIdx.x * blockDim.x + threadIdx.x;
  int stride = gridDim.x * blockDim.x;
  for (; idx < n8; idx += stride) {
    const float4* p = (const float4*)(x + (size_t)idx * 8);
    float4 v0 = p[0], v1 = p[1];
    bf16x8 o;
    o[0] = (short)f2bf(v0.x); o[1] = (short)f2bf(v0.y);
    o[2] = (short)f2bf(v0.z); o[3] = (short)f2bf(v0.w);
    o[4] = (short)f2bf(v1.x); o[5] = (short)f2bf(v1.y);
    o[6] = (short)f2bf(v1.z); o[7] = (short)f2bf(v1.w);
    *(bf16x8*)(y + (size_t)idx * 8) = o;
  }
}

// ---------------- transpose + cast: W[K][N] f32 -> Wt[N][K] bf16 ----------------
__global__ void transpose_cast(const float* __restrict__ W, unsigned short* __restrict__ Wt,
                               int Kdim, int Nw) {
  __shared__ float tile[32][33];
  int n0 = blockIdx.x * 32, k0 = blockIdx.y * 32;
  int tx = threadIdx.x, ty = threadIdx.y;
#pragma unroll
  for (int r = ty; r < 32; r += 8)
    tile[r][tx] = W[(size_t)(k0 + r) * Nw + n0 + tx];
  __syncthreads();
#pragma unroll
  for (int r = ty; r < 32; r += 8)
    Wt[(size_t)(n0 + r) * Kdim + k0 + tx] = f2bf(tile[tx][r]);
}

// ---------------- GEMM (m97 structure): A[M][K] x Bt[N][K] -------------------
// T1 XCD swizzle: column-chunked, bijective (nwg % 8 == 0, gridDim.y == 32).
// EPI==1 fuses QK RMS-norm into the epilogue. (256,3): 3 blocks/CU -> 12 waves/CU
// (m97's occupancy; kills gemm1's 768-block tail at 2/CU).
template <int EPI>
__global__ __launch_bounds__(256, 3)
void gemm_bt(const unsigned short* __restrict__ A, const unsigned short* __restrict__ Bt,
             int Kr, float* __restrict__ Cf, int Nr,
             unsigned short* __restrict__ Qn, unsigned short* __restrict__ Kn,
             unsigned short* __restrict__ Vt, float qscale) {
  __shared__ __align__(16) unsigned short lsA[128 * 32];
  __shared__ __align__(16) unsigned short lsB[128 * 32];
  const int t = threadIdx.x;
  const int lane = t & 63;
  const int w = t >> 6, wr = w >> 1, wc = w & 1;
  const int lo = lane & 15, hi = lane >> 4;
  const int nwg = gridDim.x * 32;
  const int bid0 = blockIdx.y * gridDim.x + blockIdx.x;
  const int sw = (bid0 & 7) * (nwg >> 3) + (bid0 >> 3);
  const int m0 = (sw & 31) * 128, n0 = (sw >> 5) * 128;

  const int c0 = t, c1 = t + 256;
  const unsigned short* gA0 = A + (size_t)(m0 + (c0 >> 2)) * Kr + (c0 & 3) * 8;
  const unsigned short* gA1 = A + (size_t)(m0 + (c1 >> 2)) * Kr + (c1 & 3) * 8;
  const unsigned short* gB0 = Bt + (size_t)(n0 + (c0 >> 2)) * Kr + (c0 & 3) * 8;
  const unsigned short* gB1 = Bt + (size_t)(n0 + (c1 >> 2)) * Kr + (c1 & 3) * 8;
  unsigned short* lA0 = lsA + c0 * 8;
  unsigned short* lA1 = lsA + c1 * 8;
  unsigned short* lB0 = lsB + c0 * 8;
  unsigned short* lB1 = lsB + c1 * 8;

  f32x4 acc[4][4] = {};

  for (int kt = 0; kt < Kr; kt += 32) {
    async16(lA0, gA0 + kt);
    async16(lA1, gA1 + kt);
    async16(lB0, gB0 + kt);
    async16(lB1, gB1 + kt);
    __syncthreads();
    bf16x8 af[4], bfr[4];
#pragma unroll
    for (int i = 0; i < 4; ++i) {
      af[i]  = *(const bf16x8*)&lsA[(wr * 64 + i * 16 + lo) * 32 + hi * 8];
      bfr[i] = *(const bf16x8*)&lsB[(wc * 64 + i * 16 + lo) * 32 + hi * 8];
    }
#pragma unroll
    for (int mi = 0; mi < 4; ++mi)
#pragma unroll
      for (int ni = 0; ni < 4; ++ni)
        acc[mi][ni] = __builtin_amdgcn_mfma_f32_16x16x32_bf16(af[mi], bfr[ni], acc[mi][ni], 0, 0, 0);
    __syncthreads();
  }

  // ---- fused QK RMS-norm factors (EPI==1, Q/K blocks only) ----
  float rr[4][4];
  if (EPI == 1 && n0 < 2560) {
    const float scl = (n0 < 2048) ? qscale : 1.0f;
    float p[4][4];
#pragma unroll
    for (int mi = 0; mi < 4; ++mi)
#pragma unroll
      for (int i = 0; i < 4; ++i) {
        float s = 0.f;
#pragma unroll
        for (int ni = 0; ni < 4; ++ni) s += acc[mi][ni][i] * acc[mi][ni][i];
        p[mi][i] = s;
      }
#pragma unroll
    for (int off = 1; off < 16; off <<= 1)
#pragma unroll
      for (int mi = 0; mi < 4; ++mi)
#pragma unroll
        for (int i = 0; i < 4; ++i) p[mi][i] += __shfl_xor(p[mi][i], off, 64);
    float* red = (float*)lsA;   // [4 wr][2 wc][64 rows] floats = 2 KB (lsA dead)
    if (lo == 0)
#pragma unroll
      for (int mi = 0; mi < 4; ++mi)
#pragma unroll
        for (int i = 0; i < 4; ++i)
          red[(wr * 2 + wc) * 64 + mi * 16 + hi * 4 + i] = p[mi][i];
    __syncthreads();
#pragma unroll
    for (int mi = 0; mi < 4; ++mi)
#pragma unroll
      for (int i = 0; i < 4; ++i) {
        float tot = p[mi][i] + red[(wr * 2 + (wc ^ 1)) * 64 + mi * 16 + hi * 4 + i];
        rr[mi][i] = rsqrtf(tot * (1.0f / 128.0f) + 1e-6f) * scl;
      }
  }

#pragma unroll
  for (int mi = 0; mi < 4; ++mi)
#pragma unroll
    for (int ni = 0; ni < 4; ++ni)
#pragma unroll
      for (int i = 0; i < 4; ++i) {
        int gm = m0 + wr * 64 + mi * 16 + hi * 4 + i;
        int gn = n0 + wc * 64 + ni * 16 + lo;
        float v = acc[mi][ni][i];
        if (EPI == 0) {
          Cf[(size_t)gm * Nr + gn] = v;
        } else {
          if (n0 < 2560) v *= rr[mi][i];        // fused RMS-norm (Q: +qscale)
          unsigned short bv = f2bf(v);
          int bb = gm >> 11, tt = gm & 2047;
          if (gn < 2048) {                      // Q: [b][h][t][d]
            int hh = gn >> 7, dd = gn & 127;
            Qn[(((size_t)bb * 16 + hh) * 2048 + tt) * 128 + dd] = bv;
          } else if (gn < 2560) {               // K: [b][hkv][t][d]
            int g2 = gn - 2048, hh = g2 >> 7, dd = g2 & 127;
            Kn[(((size_t)bb * 4 + hh) * 2048 + tt) * 128 + dd] = bv;
          } else {                              // V^T: [b][hkv][d][t]
            int g2 = gn - 2560, hh = g2 >> 7, dd = g2 & 127;
            Vt[(((size_t)bb * 4 + hh) * 128 + dd) * 2048 + tt] = bv;
          }
        }
      }
}

// ---------------- flash attention: swapped-QK^T 32x32 MFMA, in-register softmax
__global__ __launch_bounds__(256, 2)
void attn(const unsigned short* __restrict__ Q, const unsigned short* __restrict__ Kk,
          const unsigned short* __restrict__ Vt, unsigned short* __restrict__ AO) {
  const int bid = blockIdx.x;
  const int bh = (bid & 7) + 8 * (bid >> 7);   // XCD swizzle (512 % 8 == 0, bijective)
  const int qx = (bid >> 3) & 15;
  const int b = bh >> 4, h = bh & 15;
  const int hkv = h >> 2;
  const int t = threadIdx.x;
  const int w = t >> 6, lane = t & 63;
  const int qi = lane & 31, h1 = lane >> 5;
  const unsigned short* Qb = Q  + (size_t)bh * 2048 * 128;
  const unsigned short* Kb = Kk + (size_t)(b * 4 + hkv) * 2048 * 128;
  const unsigned short* Vb = Vt + (size_t)(b * 4 + hkv) * 128 * 2048;
  const int q0 = qx * 128 + w * 32;

  __shared__ __align__(16) unsigned short Klds[2][64 * 128];  // 32 KB, granule^(row&15)
  __shared__ __align__(16) unsigned short Vlds[2][128 * 64];  // 32 KB, granule^(row&7)

  bf16x8 qf[8];
#pragma unroll
  for (int s = 0; s < 8; ++s)
    qf[s] = *(const bf16x8*)&Qb[(size_t)(q0 + qi) * 128 + s * 16 + h1 * 8];

  f32x16 Oc[4] = {};            // O^T acc: col=q (lane), row=d-offset
  float mrow = -1e30f, srow = 0.f;

#define STAGE_KV(bufi, kt_)                                                      \
  {                                                                              \
    const unsigned short* gK = Kb + (size_t)(kt_) * 128;                         \
    const unsigned short* gV = Vb + (kt_);                                       \
    _Pragma("unroll")                                                            \
    for (int j = 0; j < 4; ++j) {                                                \
      int gi = j * 256 + t;                                                      \
      int kr = gi >> 4, kg = (gi & 15) ^ (kr & 15);                              \
      async16(&Klds[bufi][gi * 8], gK + (size_t)kr * 128 + kg * 8);              \
      int vr = gi >> 3, vg = (gi & 7) ^ (vr & 7);                                \
      async16(&Vlds[bufi][gi * 8], gV + (size_t)vr * 2048 + vg * 8);             \
    }                                                                            \
  }

  STAGE_KV(0, 0);
  __syncthreads();

  int cur = 0;
  for (int kt = 0; kt < 2048; kt += 64) {
    if (kt + 64 < 2048) STAGE_KV(cur ^ 1, kt + 64);

    const unsigned short* KL = Klds[cur];
    const unsigned short* VL = Vlds[cur];

    // ---- QK^T (swapped): S[mt] = K_tile^T-frag x Q-frag; lane q = qi ----
    f32x16 S[2] = {};
    __builtin_amdgcn_s_setprio(1);
#pragma unroll
    for (int mt = 0; mt < 2; ++mt) {
      const int krow = mt * 32 + qi;
      const unsigned short* krp = KL + krow * 128;
      const int rswz = krow & 15;
#pragma unroll
      for (int s = 0; s < 8; ++s) {
        bf16x8 kf = *(const bf16x8*)(krp + (((2 * s + h1) ^ rswz) << 3));
        S[mt] = __builtin_amdgcn_mfma_f32_32x32x16_bf16(kf, qf[s], S[mt], 0, 0, 0);
      }
    }
    __builtin_amdgcn_s_setprio(0);
    // lane holds P[q=qi][key = mt*32 + (r&3) + 8*(r>>2) + 4*h1], r=0..15

    // ---- in-register online softmax (base-2), tree reductions ----
    float t8[8];
#pragma unroll
    for (int r = 0; r < 8; ++r)
      t8[r] = fmaxf(fmaxf(S[0][r], S[0][r + 8]), fmaxf(S[1][r], S[1][r + 8]));
#pragma unroll
    for (int r = 0; r < 4; ++r) t8[r] = fmaxf(t8[r], t8[r + 4]);
    float mx = fmaxf(fmaxf(t8[0], t8[1]), fmaxf(t8[2], t8[3]));
    mx = fmaxf(mx, __shfl_xor(mx, 32, 64));
    if (__any(mx > mrow + 8.0f)) {             // defer-max THR=8 (base-2)
      float mnew = fmaxf(mrow, mx);
      float al = __builtin_amdgcn_exp2f(mrow - mnew);
      mrow = mnew;
      srow *= al;
#pragma unroll
      for (int dt = 0; dt < 4; ++dt)
#pragma unroll
        for (int r = 0; r < 16; ++r) Oc[dt][r] *= al;
    }
#pragma unroll
    for (int mt = 0; mt < 2; ++mt)
#pragma unroll
      for (int r = 0; r < 16; ++r)
        S[mt][r] = __builtin_amdgcn_exp2f(S[mt][r] - mrow);
    float s8[8];
#pragma unroll
    for (int r = 0; r < 8; ++r)
      s8[r] = (S[0][r] + S[0][r + 8]) + (S[1][r] + S[1][r + 8]);
#pragma unroll
    for (int r = 0; r < 4; ++r) s8[r] += s8[r + 4];
    float rs = (s8[0] + s8[1]) + (s8[2] + s8[3]);
    rs += __shfl_xor(rs, 32, 64);
    srow += rs;

    // ---- P -> bf16 (HW cvt_pk), cross-half exchange, PV ----
    __builtin_amdgcn_s_setprio(1);
#pragma unroll
    for (int mt = 0; mt < 2; ++mt) {
      unsigned wd[8];
#pragma unroll
      for (int i2 = 0; i2 < 8; ++i2) wd[i2] = cvtpk(S[mt][2 * i2], S[mt][2 * i2 + 1]);
      unsigned r0 = __shfl_xor(h1 ? wd[0] : wd[2], 32, 64);
      unsigned r1 = __shfl_xor(h1 ? wd[1] : wd[3], 32, 64);
      unsigned r2 = __shfl_xor(h1 ? wd[4] : wd[6], 32, 64);
      unsigned r3 = __shfl_xor(h1 ? wd[5] : wd[7], 32, 64);
      bf16x8 pf0 = frag4(h1 ? r0 : wd[0], h1 ? r1 : wd[1], h1 ? wd[2] : r0, h1 ? wd[3] : r1);
      bf16x8 pf1 = frag4(h1 ? r2 : wd[4], h1 ? r3 : wd[5], h1 ? wd[6] : r2, h1 ? wd[7] : r3);
#pragma unroll
      for (int dt = 0; dt < 4; ++dt) {
        const int vrow = dt * 32 + qi;
        const unsigned short* vrp = VL + vrow * 64;
        const int vswz = vrow & 7;
        bf16x8 v0 = *(const bf16x8*)(vrp + (((mt * 4 + 0 + h1) ^ vswz) << 3));
        bf16x8 v1 = *(const bf16x8*)(vrp + (((mt * 4 + 2 + h1) ^ vswz) << 3));
        Oc[dt] = __builtin_amdgcn_mfma_f32_32x32x16_bf16(v0, pf0, Oc[dt], 0, 0, 0);
        Oc[dt] = __builtin_amdgcn_mfma_f32_32x32x16_bf16(v1, pf1, Oc[dt], 0, 0, 0);
      }
    }
    __builtin_amdgcn_s_setprio(0);

    __syncthreads();  // prefetch landed + all LDS reads done before overwrite
    cur ^= 1;
  }

  // ---- epilogue: O = Oc / srow; lane writes 32 d-values for its q row ----
  const float inv = 1.0f / srow;
  const size_t orow = ((size_t)(b * 2048 + q0 + qi)) * 2048 + h * 128;
#pragma unroll
  for (int dt = 0; dt < 4; ++dt)
#pragma unroll
    for (int rq = 0; rq < 4; ++rq) {
      int d0 = dt * 32 + 8 * rq + 4 * h1;
      unsigned u0 = cvtpk(Oc[dt][4 * rq + 0] * inv, Oc[dt][4 * rq + 1] * inv);
      unsigned u1 = cvtpk(Oc[dt][4 * rq + 2] * inv, Oc[dt][4 * rq + 3] * inv);
      uint2 st = {u0, u1};
      *(uint2*)((unsigned short*)AO + orow + d0) = st;
    }
}

// ------------------------------- launcher -------------------------------------
extern "C" void kernel_launch(void* const* d_in, const int* in_sizes, int n_in,
                              void* d_out, int out_size, void* d_ws, size_t ws_size,
                              hipStream_t stream) {
  const float* x_q = (const float*)d_in[0];
  const float* Wq  = (const float*)d_in[1];
  const float* Wk  = (const float*)d_in[2];
  const float* Wv  = (const float*)d_in[3];
  const float* Wo  = (const float*)d_in[4];
  float* out = (float*)d_out;

  char* ws = (char*)d_ws;
  unsigned short* Xb    = (unsigned short*)(ws);             // 16.8 MB (reused as AO)
  unsigned short* WqkvT = (unsigned short*)(ws + 16777216);  // 12.6 MB
  unsigned short* WoT   = (unsigned short*)(ws + 29360128);  //  8.4 MB
  unsigned short* Qn    = (unsigned short*)(ws + 37748736);  // 16.8 MB
  unsigned short* Kn    = (unsigned short*)(ws + 54525952);  //  4.2 MB
  unsigned short* Vt    = (unsigned short*)(ws + 58720256);  //  4.2 MB
  unsigned short* AO    = Xb;

  cast_x<<<2048, 256, 0, stream>>>(x_q, Xb, (4096 * 2048) / 8);
  transpose_cast<<<dim3(2048 / 32, 2048 / 32), dim3(32, 8), 0, stream>>>(Wq, WqkvT, 2048, 2048);
  transpose_cast<<<dim3(512 / 32, 2048 / 32), dim3(32, 8), 0, stream>>>(Wk, WqkvT + 2048 * 2048, 2048, 512);
  transpose_cast<<<dim3(512 / 32, 2048 / 32), dim3(32, 8), 0, stream>>>(Wv, WqkvT + 2560 * 2048, 2048, 512);
  transpose_cast<<<dim3(2048 / 32, 2048 / 32), dim3(32, 8), 0, stream>>>(Wo, WoT, 2048, 2048);

  // Q scale = (1/sqrt(128)) * log2(e) -> softmax runs in base-2 (norm fused in epilogue)
  gemm_bt<1><<<dim3(3072 / 128, 4096 / 128), 256, 0, stream>>>(Xb, WqkvT, 2048, nullptr, 0,
                                                               Qn, Kn, Vt, 0.12751742f);
  attn<<<512, 256, 0, stream>>>(Qn, Kn, Vt, AO);
  gemm_bt<0><<<dim3(2048 / 128, 4096 / 128), 256, 0, stream>>>(AO, WoT, 2048, out, 2048,
                                                               nullptr, nullptr, nullptr, 0.f);
}

// Round 14
// 214.286 us; speedup vs baseline: 1.2214x; 1.1143x over previous
//
#include <hip/hip_runtime.h>

typedef __attribute__((ext_vector_type(4))) float f32x4;
typedef __attribute__((ext_vector_type(16))) float f32x16;
typedef __attribute__((ext_vector_type(8))) short bf16x8;
typedef __attribute__((ext_vector_type(4))) unsigned u32x4;

#define DEV __device__ __forceinline__

DEV unsigned short f2bf(float f) {            // RTNE f32 -> bf16
  unsigned u = __float_as_uint(f);
  unsigned r = (u + 0x7FFFu + ((u >> 16) & 1u)) >> 16;
  return (unsigned short)r;
}
DEV float bf2f(unsigned short h) { return __uint_as_float(((unsigned)h) << 16); }

DEV unsigned cvtpk(float lo, float hi) {      // packed f32x2 -> bf16x2 (HW RTNE)
  unsigned r;
  asm("v_cvt_pk_bf16_f32 %0, %1, %2" : "=v"(r) : "v"(lo), "v"(hi));
  return r;
}
DEV bf16x8 frag4(unsigned a, unsigned b, unsigned c, unsigned d) {
  u32x4 u = {a, b, c, d};
  return __builtin_bit_cast(bf16x8, u);
}

typedef __attribute__((address_space(1))) void gas_t;
typedef __attribute__((address_space(3))) void las_t;
DEV void async16(void* lds, const void* g) {
  __builtin_amdgcn_global_load_lds((gas_t*)g, (las_t*)lds, 16, 0, 0);
}

// ------- fused prep: cast x -> bf16 (region 0) + 4 W transposes (regions 1-4) --
__global__ __launch_bounds__(256)
void prep(const float* __restrict__ x, const float* __restrict__ Wq,
          const float* __restrict__ Wk, const float* __restrict__ Wv,
          const float* __restrict__ Wo, unsigned short* __restrict__ Xb,
          unsigned short* __restrict__ WqkvT, unsigned short* __restrict__ WoT) {
  const int bid = blockIdx.x, t = threadIdx.x;
  if (bid < 512) {                              // ---- cast x: 8 bf16/thread/iter
    int idx = bid * 256 + t;
    for (; idx < 1048576; idx += 131072) {
      const float4* p = (const float4*)(x + (size_t)idx * 8);
      float4 v0 = p[0], v1 = p[1];
      bf16x8 o;
      o[0] = (short)f2bf(v0.x); o[1] = (short)f2bf(v0.y);
      o[2] = (short)f2bf(v0.z); o[3] = (short)f2bf(v0.w);
      o[4] = (short)f2bf(v1.x); o[5] = (short)f2bf(v1.y);
      o[6] = (short)f2bf(v1.z); o[7] = (short)f2bf(v1.w);
      *(bf16x8*)(Xb + (size_t)idx * 8) = o;
    }
    return;
  }
  // ---- transpose+cast W[K][N] -> Wt[N][K], 32x32 tiles, Kdim = 2048 ----
  const float* W;
  unsigned short* Wt;
  int n0, k0, Nw;
  if (bid < 4608)      { int b2 = bid - 512;  W = Wq; Wt = WqkvT;              Nw = 2048; n0 = (b2 & 63) * 32; k0 = (b2 >> 6) * 32; }
  else if (bid < 5632) { int b2 = bid - 4608; W = Wk; Wt = WqkvT + 2048 * 2048; Nw = 512;  n0 = (b2 & 15) * 32; k0 = (b2 >> 4) * 32; }
  else if (bid < 6656) { int b2 = bid - 5632; W = Wv; Wt = WqkvT + 2560 * 2048; Nw = 512;  n0 = (b2 & 15) * 32; k0 = (b2 >> 4) * 32; }
  else                 { int b2 = bid - 6656; W = Wo; Wt = WoT;                Nw = 2048; n0 = (b2 & 63) * 32; k0 = (b2 >> 6) * 32; }
  __shared__ float tile[32][33];
  const int tx = t & 31, ty = t >> 5;
#pragma unroll
  for (int r = ty; r < 32; r += 8)
    tile[r][tx] = W[(size_t)(k0 + r) * Nw + n0 + tx];
  __syncthreads();
#pragma unroll
  for (int r = ty; r < 32; r += 8)
    Wt[(size_t)(n0 + r) * 2048 + k0 + tx] = f2bf(tile[tx][r]);
}

// ---------------- GEMM (m97 structure, BK=64): A[M][K] x Bt[N][K] ------------
// Single-buffer 2-barrier loop; BK=64 halves barrier count vs BK=32.
// LDS rows are 128B -> granule^(row&7) XOR swizzle (pre-swizzled source, rule #21).
// T1 XCD swizzle (nwg % 8 == 0). EPI==1 fuses QK RMS-norm into the epilogue.
template <int EPI>
__global__ __launch_bounds__(256, 3)
void gemm_bt(const unsigned short* __restrict__ A, const unsigned short* __restrict__ Bt,
             int Kr, float* __restrict__ Cf, int Nr,
             unsigned short* __restrict__ Qn, unsigned short* __restrict__ Kn,
             unsigned short* __restrict__ Vt, float qscale) {
  __shared__ __align__(16) unsigned short lsA[128 * 64];   // 16 KB
  __shared__ __align__(16) unsigned short lsB[128 * 64];   // 16 KB
  const int t = threadIdx.x;
  const int lane = t & 63;
  const int w = t >> 6, wr = w >> 1, wc = w & 1;
  const int lo = lane & 15, hi = lane >> 4;
  const int swz = lo & 7;
  const int nwg = gridDim.x * 32;
  const int bid0 = blockIdx.y * gridDim.x + blockIdx.x;
  const int sw = (bid0 & 7) * (nwg >> 3) + (bid0 >> 3);
  const int m0 = (sw & 31) * 128, n0 = (sw >> 5) * 128;

  f32x4 acc[4][4] = {};

  for (int kt = 0; kt < Kr; kt += 64) {
    // stage A,B tiles (128 rows x 64 cols, 8 granules/row, source pre-swizzled)
#pragma unroll
    for (int j = 0; j < 4; ++j) {
      int gi = j * 256 + t;
      int rw = gi >> 3, g = (gi & 7) ^ (rw & 7);
      async16(lsA + gi * 8, A + (size_t)(m0 + rw) * Kr + kt + g * 8);
      async16(lsB + gi * 8, Bt + (size_t)(n0 + rw) * Kr + kt + g * 8);
    }
    __syncthreads();  // drains vmcnt -> tiles ready
#pragma unroll
    for (int kk = 0; kk < 2; ++kk) {
      bf16x8 af[4], bfr[4];
#pragma unroll
      for (int i = 0; i < 4; ++i) {
        af[i]  = *(const bf16x8*)&lsA[(wr * 64 + i * 16 + lo) * 64 + (((kk * 4 + hi) ^ swz) << 3)];
        bfr[i] = *(const bf16x8*)&lsB[(wc * 64 + i * 16 + lo) * 64 + (((kk * 4 + hi) ^ swz) << 3)];
      }
#pragma unroll
      for (int mi = 0; mi < 4; ++mi)
#pragma unroll
        for (int ni = 0; ni < 4; ++ni)
          acc[mi][ni] = __builtin_amdgcn_mfma_f32_16x16x32_bf16(af[mi], bfr[ni], acc[mi][ni], 0, 0, 0);
    }
    __syncthreads();  // all reads done before next stage overwrites
  }

  // ---- fused QK RMS-norm factors (EPI==1, Q/K blocks only) ----
  float rr[4][4];
  if (EPI == 1 && n0 < 2560) {
    const float scl = (n0 < 2048) ? qscale : 1.0f;
    float p[4][4];
#pragma unroll
    for (int mi = 0; mi < 4; ++mi)
#pragma unroll
      for (int i = 0; i < 4; ++i) {
        float s = 0.f;
#pragma unroll
        for (int ni = 0; ni < 4; ++ni) s += acc[mi][ni][i] * acc[mi][ni][i];
        p[mi][i] = s;
      }
#pragma unroll
    for (int off = 1; off < 16; off <<= 1)
#pragma unroll
      for (int mi = 0; mi < 4; ++mi)
#pragma unroll
        for (int i = 0; i < 4; ++i) p[mi][i] += __shfl_xor(p[mi][i], off, 64);
    float* red = (float*)lsA;   // [4 wr][2 wc][64 rows] floats = 2 KB (lsA dead)
    if (lo == 0)
#pragma unroll
      for (int mi = 0; mi < 4; ++mi)
#pragma unroll
        for (int i = 0; i < 4; ++i)
          red[(wr * 2 + wc) * 64 + mi * 16 + hi * 4 + i] = p[mi][i];
    __syncthreads();
#pragma unroll
    for (int mi = 0; mi < 4; ++mi)
#pragma unroll
      for (int i = 0; i < 4; ++i) {
        float tot = p[mi][i] + red[(wr * 2 + (wc ^ 1)) * 64 + mi * 16 + hi * 4 + i];
        rr[mi][i] = rsqrtf(tot * (1.0f / 128.0f) + 1e-6f) * scl;
      }
  }

#pragma unroll
  for (int mi = 0; mi < 4; ++mi)
#pragma unroll
    for (int ni = 0; ni < 4; ++ni)
#pragma unroll
      for (int i = 0; i < 4; ++i) {
        int gm = m0 + wr * 64 + mi * 16 + hi * 4 + i;
        int gn = n0 + wc * 64 + ni * 16 + lo;
        float v = acc[mi][ni][i];
        if (EPI == 0) {
          Cf[(size_t)gm * Nr + gn] = v;
        } else {
          if (n0 < 2560) v *= rr[mi][i];        // fused RMS-norm (Q: +qscale)
          unsigned short bv = f2bf(v);
          int bb = gm >> 11, tt = gm & 2047;
          if (gn < 2048) {                      // Q: [b][h][t][d]
            int hh = gn >> 7, dd = gn & 127;
            Qn[(((size_t)bb * 16 + hh) * 2048 + tt) * 128 + dd] = bv;
          } else if (gn < 2560) {               // K: [b][hkv][t][d]
            int g2 = gn - 2048, hh = g2 >> 7, dd = g2 & 127;
            Kn[(((size_t)bb * 4 + hh) * 2048 + tt) * 128 + dd] = bv;
          } else {                              // V^T: [b][hkv][d][t]
            int g2 = gn - 2560, hh = g2 >> 7, dd = g2 & 127;
            Vt[(((size_t)bb * 4 + hh) * 128 + dd) * 2048 + tt] = bv;
          }
        }
      }
}

// ---------------- flash attention: swapped-QK^T 32x32 MFMA, in-register softmax
__global__ __launch_bounds__(256, 2)
void attn(const unsigned short* __restrict__ Q, const unsigned short* __restrict__ Kk,
          const unsigned short* __restrict__ Vt, unsigned short* __restrict__ AO) {
  const int bid = blockIdx.x;
  const int bh = (bid & 7) + 8 * (bid >> 7);   // XCD swizzle (512 % 8 == 0, bijective)
  const int qx = (bid >> 3) & 15;
  const int b = bh >> 4, h = bh & 15;
  const int hkv = h >> 2;
  const int t = threadIdx.x;
  const int w = t >> 6, lane = t & 63;
  const int qi = lane & 31, h1 = lane >> 5;
  const unsigned short* Qb = Q  + (size_t)bh * 2048 * 128;
  const unsigned short* Kb = Kk + (size_t)(b * 4 + hkv) * 2048 * 128;
  const unsigned short* Vb = Vt + (size_t)(b * 4 + hkv) * 128 * 2048;
  const int q0 = qx * 128 + w * 32;

  __shared__ __align__(16) unsigned short Klds[2][64 * 128];  // 32 KB, granule^(row&15)
  __shared__ __align__(16) unsigned short Vlds[2][128 * 64];  // 32 KB, granule^(row&7)

  bf16x8 qf[8];
#pragma unroll
  for (int s = 0; s < 8; ++s)
    qf[s] = *(const bf16x8*)&Qb[(size_t)(q0 + qi) * 128 + s * 16 + h1 * 8];

  f32x16 Oc[4] = {};            // O^T acc: col=q (lane), row=d-offset
  float mrow = -1e30f, srow = 0.f;

#define STAGE_KV(bufi, kt_)                                                      \
  {                                                                              \
    const unsigned short* gK = Kb + (size_t)(kt_) * 128;                         \
    const unsigned short* gV = Vb + (kt_);                                       \
    _Pragma("unroll")                                                            \
    for (int j = 0; j < 4; ++j) {                                                \
      int gi = j * 256 + t;                                                      \
      int kr = gi >> 4, kg = (gi & 15) ^ (kr & 15);                              \
      async16(&Klds[bufi][gi * 8], gK + (size_t)kr * 128 + kg * 8);              \
      int vr = gi >> 3, vg = (gi & 7) ^ (vr & 7);                                \
      async16(&Vlds[bufi][gi * 8], gV + (size_t)vr * 2048 + vg * 8);             \
    }                                                                            \
  }

  STAGE_KV(0, 0);
  __syncthreads();

  int cur = 0;
  for (int kt = 0; kt < 2048; kt += 64) {
    if (kt + 64 < 2048) STAGE_KV(cur ^ 1, kt + 64);

    const unsigned short* KL = Klds[cur];
    const unsigned short* VL = Vlds[cur];

    // ---- QK^T (swapped): S[mt] = K_tile^T-frag x Q-frag; lane q = qi ----
    f32x16 S[2] = {};
    __builtin_amdgcn_s_setprio(1);
#pragma unroll
    for (int mt = 0; mt < 2; ++mt) {
      const int krow = mt * 32 + qi;
      const unsigned short* krp = KL + krow * 128;
      const int rswz = krow & 15;
#pragma unroll
      for (int s = 0; s < 8; ++s) {
        bf16x8 kf = *(const bf16x8*)(krp + (((2 * s + h1) ^ rswz) << 3));
        S[mt] = __builtin_amdgcn_mfma_f32_32x32x16_bf16(kf, qf[s], S[mt], 0, 0, 0);
      }
    }
    __builtin_amdgcn_s_setprio(0);
    // lane holds P[q=qi][key = mt*32 + (r&3) + 8*(r>>2) + 4*h1], r=0..15

    // ---- in-register online softmax (base-2), tree reductions ----
    float t8[8];
#pragma unroll
    for (int r = 0; r < 8; ++r)
      t8[r] = fmaxf(fmaxf(S[0][r], S[0][r + 8]), fmaxf(S[1][r], S[1][r + 8]));
#pragma unroll
    for (int r = 0; r < 4; ++r) t8[r] = fmaxf(t8[r], t8[r + 4]);
    float mx = fmaxf(fmaxf(t8[0], t8[1]), fmaxf(t8[2], t8[3]));
    mx = fmaxf(mx, __shfl_xor(mx, 32, 64));
    if (__any(mx > mrow + 8.0f)) {             // defer-max THR=8 (base-2)
      float mnew = fmaxf(mrow, mx);
      float al = __builtin_amdgcn_exp2f(mrow - mnew);
      mrow = mnew;
      srow *= al;
#pragma unroll
      for (int dt = 0; dt < 4; ++dt)
#pragma unroll
        for (int r = 0; r < 16; ++r) Oc[dt][r] *= al;
    }
#pragma unroll
    for (int mt = 0; mt < 2; ++mt)
#pragma unroll
      for (int r = 0; r < 16; ++r)
        S[mt][r] = __builtin_amdgcn_exp2f(S[mt][r] - mrow);
    float s8[8];
#pragma unroll
    for (int r = 0; r < 8; ++r)
      s8[r] = (S[0][r] + S[0][r + 8]) + (S[1][r] + S[1][r + 8]);
#pragma unroll
    for (int r = 0; r < 4; ++r) s8[r] += s8[r + 4];
    float rs = (s8[0] + s8[1]) + (s8[2] + s8[3]);
    rs += __shfl_xor(rs, 32, 64);
    srow += rs;

    // ---- P -> bf16 (HW cvt_pk), cross-half exchange, PV ----
    __builtin_amdgcn_s_setprio(1);
#pragma unroll
    for (int mt = 0; mt < 2; ++mt) {
      unsigned wd[8];
#pragma unroll
      for (int i2 = 0; i2 < 8; ++i2) wd[i2] = cvtpk(S[mt][2 * i2], S[mt][2 * i2 + 1]);
      unsigned r0 = __shfl_xor(h1 ? wd[0] : wd[2], 32, 64);
      unsigned r1 = __shfl_xor(h1 ? wd[1] : wd[3], 32, 64);
      unsigned r2 = __shfl_xor(h1 ? wd[4] : wd[6], 32, 64);
      unsigned r3 = __shfl_xor(h1 ? wd[5] : wd[7], 32, 64);
      bf16x8 pf0 = frag4(h1 ? r0 : wd[0], h1 ? r1 : wd[1], h1 ? wd[2] : r0, h1 ? wd[3] : r1);
      bf16x8 pf1 = frag4(h1 ? r2 : wd[4], h1 ? r3 : wd[5], h1 ? wd[6] : r2, h1 ? wd[7] : r3);
#pragma unroll
      for (int dt = 0; dt < 4; ++dt) {
        const int vrow = dt * 32 + qi;
        const unsigned short* vrp = VL + vrow * 64;
        const int vswz = vrow & 7;
        bf16x8 v0 = *(const bf16x8*)(vrp + (((mt * 4 + 0 + h1) ^ vswz) << 3));
        bf16x8 v1 = *(const bf16x8*)(vrp + (((mt * 4 + 2 + h1) ^ vswz) << 3));
        Oc[dt] = __builtin_amdgcn_mfma_f32_32x32x16_bf16(v0, pf0, Oc[dt], 0, 0, 0);
        Oc[dt] = __builtin_amdgcn_mfma_f32_32x32x16_bf16(v1, pf1, Oc[dt], 0, 0, 0);
      }
    }
    __builtin_amdgcn_s_setprio(0);

    __syncthreads();  // prefetch landed + all LDS reads done before overwrite
    cur ^= 1;
  }

  // ---- epilogue: O = Oc / srow; lane writes 32 d-values for its q row ----
  const float inv = 1.0f / srow;
  const size_t orow = ((size_t)(b * 2048 + q0 + qi)) * 2048 + h * 128;
#pragma unroll
  for (int dt = 0; dt < 4; ++dt)
#pragma unroll
    for (int rq = 0; rq < 4; ++rq) {
      int d0 = dt * 32 + 8 * rq + 4 * h1;
      unsigned u0 = cvtpk(Oc[dt][4 * rq + 0] * inv, Oc[dt][4 * rq + 1] * inv);
      unsigned u1 = cvtpk(Oc[dt][4 * rq + 2] * inv, Oc[dt][4 * rq + 3] * inv);
      uint2 st = {u0, u1};
      *(uint2*)((unsigned short*)AO + orow + d0) = st;
    }
}

// ------------------------------- launcher -------------------------------------
extern "C" void kernel_launch(void* const* d_in, const int* in_sizes, int n_in,
                              void* d_out, int out_size, void* d_ws, size_t ws_size,
                              hipStream_t stream) {
  const float* x_q = (const float*)d_in[0];
  const float* Wq  = (const float*)d_in[1];
  const float* Wk  = (const float*)d_in[2];
  const float* Wv  = (const float*)d_in[3];
  const float* Wo  = (const float*)d_in[4];
  float* out = (float*)d_out;

  char* ws = (char*)d_ws;
  unsigned short* Xb    = (unsigned short*)(ws);             // 16.8 MB (reused as AO)
  unsigned short* WqkvT = (unsigned short*)(ws + 16777216);  // 12.6 MB
  unsigned short* WoT   = (unsigned short*)(ws + 29360128);  //  8.4 MB
  unsigned short* Qn    = (unsigned short*)(ws + 37748736);  // 16.8 MB
  unsigned short* Kn    = (unsigned short*)(ws + 54525952);  //  4.2 MB
  unsigned short* Vt    = (unsigned short*)(ws + 58720256);  //  4.2 MB
  unsigned short* AO    = Xb;

  prep<<<10752, 256, 0, stream>>>(x_q, Wq, Wk, Wv, Wo, Xb, WqkvT, WoT);

  // Q scale = (1/sqrt(128)) * log2(e) -> softmax runs in base-2 (norm fused in epilogue)
  gemm_bt<1><<<dim3(3072 / 128, 4096 / 128), 256, 0, stream>>>(Xb, WqkvT, 2048, nullptr, 0,
                                                               Qn, Kn, Vt, 0.12751742f);
  attn<<<512, 256, 0, stream>>>(Qn, Kn, Vt, AO);
  gemm_bt<0><<<dim3(2048 / 128, 4096 / 128), 256, 0, stream>>>(AO, WoT, 2048, out, 2048,
                                                               nullptr, nullptr, nullptr, 0.f);
}